// Round 1
// baseline (413.926 us; speedup 1.0000x reference)
//
#include <hip/hip_runtime.h>

// RoPE: out[...,2k]   = cos(a_k)*x[2k] - sin(a_k)*x[2k+1]
//       out[...,2k+1] = sin(a_k)*x[2k] + cos(a_k)*x[2k+1]
// a_k = pos * 10000^(-2k/128), k in [0,64), rows = 4*32*4096, D=128.
// One thread per float4 (2 pairs, 16B/lane coalesced).

#define BLOCK 256

__global__ __launch_bounds__(BLOCK) void rope_kernel(
    const float4* __restrict__ x,
    const int* __restrict__ pos,
    float4* __restrict__ out,
    int n_f4)
{
    int tid = blockIdx.x * BLOCK + threadIdx.x;
    if (tid >= n_f4) return;

    int row = tid >> 5;        // 32 float4 per row of 128
    int j   = tid & 31;        // float4 index within row -> pairs 2j, 2j+1

    float p = (float)pos[row]; // wave-broadcast load (same addr for 32 lanes)
    float4 v = x[tid];

    // inv_freq_k = 10000^(-k/64) = exp2(k * -log2(10000)/64)
    const float c = -0.2076205059304601f;  // -log2(10000)/64
    float k0 = (float)(2 * j);
    float a0 = p * exp2f(k0 * c);
    float a1 = p * exp2f((k0 + 1.0f) * c);

    float s0, c0, s1, c1;
    sincosf(a0, &s0, &c0);   // accurate version: angles up to ~4095 rad
    sincosf(a1, &s1, &c1);

    float4 r;
    r.x = c0 * v.x - s0 * v.y;
    r.y = s0 * v.x + c0 * v.y;
    r.z = c1 * v.z - s1 * v.w;
    r.w = s1 * v.z + c1 * v.w;
    out[tid] = r;
}

extern "C" void kernel_launch(void* const* d_in, const int* in_sizes, int n_in,
                              void* d_out, int out_size, void* d_ws, size_t ws_size,
                              hipStream_t stream) {
    const float4* x  = (const float4*)d_in[0];
    const int* pos   = (const int*)d_in[1];
    float4* out      = (float4*)d_out;

    int n_f4 = out_size / 4;               // 16,777,216
    int blocks = (n_f4 + BLOCK - 1) / BLOCK;
    rope_kernel<<<blocks, BLOCK, 0, stream>>>(x, pos, out, n_f4);
}